// Round 11
// baseline (142.527 us; speedup 1.0000x reference)
//
#include <hip/hip_runtime.h>

#define N_VEC   131072
#define D       64
#define KCODES  1024
#define NT      64            // code tiles of 16 (global)
#define HT      32            // tiles per code-half
#define BLK     256
#define VPB     256           // vectors per block (64 per wave: 4 b-tiles)
#define CH      4             // code tiles staged per LDS chunk
#define NCH     (HT / CH)     // 8 chunks per half

typedef __attribute__((ext_vector_type(8))) short bf16x8;
typedef __attribute__((ext_vector_type(4))) float f32x4;

// direct global->LDS 16B DMA (no VGPR round trip; LDS dest = wave base + lane*16)
#define GLD16(dst, src) __builtin_amdgcn_global_load_lds(                      \
    (const __attribute__((address_space(1))) void*)(src),                      \
    (__attribute__((address_space(3))) void*)(dst), 16, 0, 0)

// ws layout:
// [0,4096)            int counts[1024]
// [4096,4100)         float sse
// [5120,9216)         float esq[1024]
// [16384,81920)       float4 efrag[64*64]     (einit = -esq/2 in C-row fragment order)
// [81920,344064)      bf16x8 afrag[64*4*64]   (codebook hi/lo MFMA A-fragments)
// [344064,1392640)    int cand[2][N_VEC]      (per-half top-3 codes, 3 x 10 bits)

__device__ __forceinline__ float4 f4fma(float4 a, float4 b, float4 c) {
    return make_float4(fmaf(a.x, b.x, c.x), fmaf(a.y, b.y, c.y),
                       fmaf(a.z, b.z, c.z), fmaf(a.w, b.w, c.w));
}
__device__ __forceinline__ float f4rsum(float4 a) {
    return (a.x + a.y) + (a.z + a.w);
}
__device__ __forceinline__ unsigned short f2bf(float f) {
    union { float f; unsigned u; } x; x.f = f;
    unsigned r = x.u + 0x7FFFu + ((x.u >> 16) & 1u);
    return (unsigned short)(r >> 16);
}
__device__ __forceinline__ float bf2f(unsigned short h) {
    union { unsigned u; float f; } x; x.u = ((unsigned)h) << 16;
    return x.f;
}
__device__ __forceinline__ int   f_as_i(float f) { union { float f; int i; } x; x.f = f; return x.i; }
__device__ __forceinline__ float i_as_f(int i)   { union { int i; float f; } x; x.i = i; return x.f; }

// esq + codebook MFMA A-fragments (hi/lo bf16 planes) + einit fragment table.
// grid 16 x 256: block handles 4 tiles (64 codes).
__global__ void prep_kernel(const float* __restrict__ cb, float* __restrict__ esq,
                            bf16x8* __restrict__ afrag, float4* __restrict__ efrag) {
    __shared__ float sesq[64];
    const int tid = threadIdx.x;
    const int c0  = blockIdx.x * 64;
    if (tid < 64) {
        const float4* c4 = reinterpret_cast<const float4*>(cb + (size_t)(c0 + tid) * D);
        float4 p = make_float4(0.f, 0.f, 0.f, 0.f);
        #pragma unroll
        for (int i = 0; i < 16; ++i) { float4 v = c4[i]; p = f4fma(v, v, p); }
        float e = f4rsum(p);
        esq[c0 + tid] = e;
        sesq[tid] = e;
    }
    __syncthreads();
    const int tt = tid >> 6;             // local tile 0..3
    const int L  = tid & 63;
    const int t  = blockIdx.x * 4 + tt;  // global tile
    const int g  = L >> 4;
    const int r  = t * 16 + (L & 15);
    #pragma unroll
    for (int ks = 0; ks < 2; ++ks) {
        const float* src = cb + (size_t)r * D + ks * 32 + g * 8;
        bf16x8 h, l;
        #pragma unroll
        for (int e = 0; e < 8; ++e) {
            float f = src[e];
            unsigned short hb = f2bf(f);
            float lo = f - bf2f(hb);
            h[e] = (short)hb;
            l[e] = (short)f2bf(lo);
        }
        afrag[(t * 4 + ks * 2 + 0) * 64 + L] = h;
        afrag[(t * 4 + ks * 2 + 1) * 64 + L] = l;
    }
    // einit = -esq/2 in C/D fragment layout (lane reg j <-> code row g*4+j)
    float4 ef;
    ef.x = -0.5f * sesq[tt * 16 + g * 4 + 0];
    ef.y = -0.5f * sesq[tt * 16 + g * 4 + 1];
    ef.z = -0.5f * sesq[tt * 16 + g * 4 + 2];
    ef.w = -0.5f * sesq[tt * 16 + g * 4 + 3];
    efrag[t * 64 + L] = ef;
}

// descending (value, idx) lexicographic insert into sorted-3 list
__device__ __forceinline__ void insd(float ov, int og,
                                     float& v0, float& v1, float& v2,
                                     int& g0, int& g1, int& g2) {
    bool b1 = (ov > v0) || (ov == v0 && og < g0);
    bool b2 = (ov > v1) || (ov == v1 && og < g1);
    bool b3 = (ov > v2) || (ov == v2 && og < g2);
    float nv2 = b2 ? v1 : (b3 ? ov : v2);
    int   ng2 = b2 ? g1 : (b3 ? og : g2);
    float nv1 = b1 ? v0 : (b2 ? ov : v1);
    int   ng1 = b1 ? g0 : (b2 ? og : g1);
    v0 = b1 ? ov : v0;
    g0 = b1 ? og : g0;
    v1 = nv1; g1 = ng1; v2 = nv2; g2 = ng2;
}

// main scan: block = (vector group bv) x (code half hc). 1024 blocks -> 4/CU.
__launch_bounds__(BLK)
__global__ void vq_main(const float* __restrict__ z_e,
                        const float4* __restrict__ afrag4, const float4* __restrict__ efrag,
                        int* __restrict__ cand) {
    __shared__ float4 scb[2][CH * 4 * 64];   // 2 x 16 KB (double-buffered A-frags)

    const int tid  = threadIdx.x;
    const int wave = tid >> 6;
    const int L    = tid & 63;
    const int lrow = L & 15;
    const int g    = L >> 4;
    const int bv   = blockIdx.x >> 1;        // vector group
    const int hc   = blockIdx.x & 1;         // code half
    const size_t vbase = (size_t)bv * VPB + wave * 64;

    const float4* afragH = afrag4 + (size_t)hc * (HT * 4 * 64);
    const float4* efragH = efrag + (size_t)hc * (HT * 64);

    // ---- B-fragments: 4 vector-tiles of 16, hi/lo bf16 split, k = g*8+e ----
    bf16x8 zhi[4][2], zlo[4][2];
    #pragma unroll
    for (int b = 0; b < 4; ++b) {
        #pragma unroll
        for (int ks = 0; ks < 2; ++ks) {
            const float* zp = z_e + (vbase + b * 16 + lrow) * D + ks * 32 + g * 8;
            float4 u0 = *reinterpret_cast<const float4*>(zp);
            float4 u1 = *reinterpret_cast<const float4*>(zp + 4);
            float fv[8] = {u0.x, u0.y, u0.z, u0.w, u1.x, u1.y, u1.z, u1.w};
            bf16x8 h, l;
            #pragma unroll
            for (int e = 0; e < 8; ++e) {
                unsigned short hb = f2bf(fv[e]);
                float lo = fv[e] - bf2f(hb);
                h[e] = (short)hb;
                l[e] = (short)f2bf(lo);
            }
            zhi[b][ks] = h; zlo[b][ks] = l;
        }
    }

    // packed top-3 stream state (r-domain: larger = nearer code)
    float m1[4], m2[4], m3[4];
    #pragma unroll
    for (int b = 0; b < 4; ++b) { m1[b] = m2[b] = m3[b] = -INFINITY; }

    // prologue: stage chunk 0 into buffer 0
    #pragma unroll
    for (int i = 0; i < 4; ++i) GLD16(&scb[0][i * BLK + tid], afragH + i * BLK + tid);

    int cur = 0;
    for (int c = 0; c < NCH; ++c) {
        __syncthreads();   // drains vmcnt -> buf[cur] ready; prev compute done
        if (c + 1 < NCH) {
            const float4* gA = afragH + (size_t)(c + 1) * (CH * 4 * 64);
            #pragma unroll
            for (int i = 0; i < 4; ++i) GLD16(&scb[cur ^ 1][i * BLK + tid], gA + i * BLK + tid);
        }

        #pragma unroll
        for (int tt = 0; tt < CH; ++tt) {
            const int t = c * CH + tt;               // local tile in half
            const bf16x8* fr = reinterpret_cast<const bf16x8*>(&scb[cur][tt * 256]);
            bf16x8 Ah0 = fr[0 * 64 + L];
            bf16x8 Al0 = fr[1 * 64 + L];
            bf16x8 Ah1 = fr[2 * 64 + L];
            bf16x8 Al1 = fr[3 * 64 + L];
            f32x4 einit;
            {
                float4 ef = efragH[t * 64 + L];      // -esq/2, L2-resident
                einit[0] = ef.x; einit[1] = ef.y; einit[2] = ef.z; einit[3] = ef.w;
            }

            #pragma unroll
            for (int b = 0; b < 4; ++b) {
                // single 6-deep chain; C-init = -esq/2 -> r = acc = dot - esq/2
                f32x4 acc;
                acc = __builtin_amdgcn_mfma_f32_16x16x32_bf16(Ah0, zhi[b][0], einit, 0, 0, 0);
                acc = __builtin_amdgcn_mfma_f32_16x16x32_bf16(Ah0, zlo[b][0], acc, 0, 0, 0);
                acc = __builtin_amdgcn_mfma_f32_16x16x32_bf16(Al0, zhi[b][0], acc, 0, 0, 0);
                acc = __builtin_amdgcn_mfma_f32_16x16x32_bf16(Ah1, zhi[b][1], acc, 0, 0, 0);
                acc = __builtin_amdgcn_mfma_f32_16x16x32_bf16(Ah1, zlo[b][1], acc, 0, 0, 0);
                acc = __builtin_amdgcn_mfma_f32_16x16x32_bf16(Al1, zhi[b][1], acc, 0, 0, 0);

                #pragma unroll
                for (int j = 0; j < 4; ++j) {
                    // pack 8-bit local id (t*4+j < 128; complement: fmax prefers lower)
                    int komp = 255 - ((t << 2) | j);   // wave-uniform SGPR
                    float pd = i_as_f((f_as_i(acc[j]) & 0xFFFFFF00) | komp);
                    // 4-op top-3 insert (min + med3 + 2 max)
                    float mn = fminf(m2[b], pd);
                    float md = __builtin_amdgcn_fmed3f(m1[b], pd, m2[b]);
                    m1[b] = fmaxf(m1[b], pd);
                    m2[b] = md;
                    m3[b] = fmaxf(m3[b], mn);
                }
            }
        }
        cur ^= 1;
    }

    // ---- decode to global code ids + cross-lane (4 g-groups) merge ----
    const int cbase = hc * (HT * 16);
    #pragma unroll
    for (int b = 0; b < 4; ++b) {
        float v0, v1, v2; int g0, g1, g2;
        {
            int p0 = f_as_i(m1[b]), p1 = f_as_i(m2[b]), p2 = f_as_i(m3[b]);
            int c0 = 255 - (p0 & 255), c1 = 255 - (p1 & 255), c2 = 255 - (p2 & 255);
            v0 = i_as_f(p0 & ~255); g0 = cbase + (c0 >> 2) * 16 + g * 4 + (c0 & 3);
            v1 = i_as_f(p1 & ~255); g1 = cbase + (c1 >> 2) * 16 + g * 4 + (c1 & 3);
            v2 = i_as_f(p2 & ~255); g2 = cbase + (c2 >> 2) * 16 + g * 4 + (c2 & 3);
        }
        #pragma unroll
        for (int m = 16; m <= 32; m <<= 1) {
            float ov0 = __shfl_xor(v0, m), ov1 = __shfl_xor(v1, m), ov2 = __shfl_xor(v2, m);
            int   og0 = __shfl_xor(g0, m), og1 = __shfl_xor(g1, m), og2 = __shfl_xor(g2, m);
            insd(ov0, og0, v0, v1, v2, g0, g1, g2);
            insd(ov1, og1, v0, v1, v2, g0, g1, g2);
            insd(ov2, og2, v0, v1, v2, g0, g1, g2);
        }
        if (g == 0) {
            size_t n = vbase + b * 16 + lrow;
            cand[(size_t)hc * N_VEC + n] = (g0 & 1023) | ((g1 & 1023) << 10) | ((g2 & 1023) << 20);
        }
    }
}

// exact rescore of the 6-candidate union (bit-replicates reference arithmetic)
__launch_bounds__(256)
__global__ void rescore_kernel(const float* __restrict__ z_e, const float* __restrict__ cb,
                               const float* __restrict__ esq, const int* __restrict__ cand,
                               float* __restrict__ zq_out, float* __restrict__ idx_out,
                               float* __restrict__ sse, int* __restrict__ counts) {
    __shared__ int   swin[256];
    __shared__ float sred[4];
    const int tid = threadIdx.x;
    const size_t n = (size_t)blockIdx.x * 256 + tid;

    const int p0 = cand[n];
    const int p1 = cand[N_VEC + n];
    int ci[6];
    ci[0] = p0 & 1023; ci[1] = (p0 >> 10) & 1023; ci[2] = (p0 >> 20) & 1023;
    ci[3] = p1 & 1023; ci[4] = (p1 >> 10) & 1023; ci[5] = (p1 >> 20) & 1023;

    const float4* z4 = reinterpret_cast<const float4*>(z_e + n * D);
    const float4* cp[6];
    #pragma unroll
    for (int k = 0; k < 6; ++k) cp[k] = reinterpret_cast<const float4*>(cb + (size_t)ci[k] * D);

    float4 pq = make_float4(0.f, 0.f, 0.f, 0.f);
    float4 s[6];
    #pragma unroll
    for (int k = 0; k < 6; ++k) s[k] = pq;
    #pragma unroll
    for (int i = 0; i < 16; ++i) {
        float4 zz = z4[i];
        pq = f4fma(zz, zz, pq);
        #pragma unroll
        for (int k = 0; k < 6; ++k) s[k] = f4fma(zz, cp[k][i], s[k]);
    }
    const float zsq = f4rsum(pq);

    float bd = INFINITY; int bi = 0x7FFFFFFF;
    #pragma unroll
    for (int k = 0; k < 6; ++k) {
        float t1 = zsq + esq[ci[k]];
        float dd = fmaf(-2.0f, f4rsum(s[k]), t1);
        if (dd < bd || (dd == bd && ci[k] < bi)) { bd = dd; bi = ci[k]; }
    }

    idx_out[n] = (float)bi;
    atomicAdd(&counts[bi], 1);
    swin[tid] = bi;

    float v = bd;
    #pragma unroll
    for (int off = 32; off > 0; off >>= 1) v += __shfl_down(v, off);
    if ((tid & 63) == 0) sred[tid >> 6] = v;
    __syncthreads();
    if (tid == 0) atomicAdd(sse, (sred[0] + sred[1]) + (sred[2] + sred[3]));

    // coalesced z_q write: 256 vectors * 16 float4
    const float4* cb4 = reinterpret_cast<const float4*>(cb);
    float4* zq4 = reinterpret_cast<float4*>(zq_out) + (size_t)blockIdx.x * (256 * 16);
    #pragma unroll
    for (int i = 0; i < 16; ++i) {
        int mi  = i * 256 + tid;
        int vec = mi >> 4;
        int e   = mi & 15;
        zq4[mi] = cb4[(size_t)swin[vec] * 16 + e];
    }
}

__global__ void finalize_kernel(const int* __restrict__ counts, const float* __restrict__ sse,
                                float* __restrict__ out_loss, float* __restrict__ out_perp) {
    __shared__ float red[256];
    int tid = threadIdx.x;
    float hsum = 0.f;
    for (int k = tid; k < KCODES; k += 256) {
        float p = (float)counts[k] / (float)N_VEC;
        hsum += p * logf(p + 1e-12f);
    }
    red[tid] = hsum;
    __syncthreads();
    for (int s = 128; s > 0; s >>= 1) {
        if (tid < s) red[tid] += red[tid + s];
        __syncthreads();
    }
    if (tid == 0) {
        out_loss[0] = 1.25f * sse[0] / 8388608.0f;   // (1+BETA) * mean
        out_perp[0] = expf(-red[0]);
    }
}

extern "C" void kernel_launch(void* const* d_in, const int* in_sizes, int n_in,
                              void* d_out, int out_size, void* d_ws, size_t ws_size,
                              hipStream_t stream) {
    const float* z_e = (const float*)d_in[0];
    const float* cb  = (const float*)d_in[1];

    float* out  = (float*)d_out;
    float* zq   = out;
    float* idxo = out + (size_t)N_VEC * D;          // 8388608
    float* loss = idxo + N_VEC;                     // +131072
    float* perp = loss + 1;

    char* ws = (char*)d_ws;
    int*    counts = (int*)ws;
    float*  sse    = (float*)(ws + 4096);
    float*  esq    = (float*)(ws + 5120);
    float4* efrag  = (float4*)(ws + 16384);
    bf16x8* afrag  = (bf16x8*)(ws + 81920);
    int*    cand   = (int*)(ws + 344064);

    hipMemsetAsync(d_ws, 0, 5120, stream);          // zero counts + sse each call
    prep_kernel<<<16, 256, 0, stream>>>(cb, esq, afrag, efrag);
    vq_main<<<(N_VEC / VPB) * 2, BLK, 0, stream>>>(z_e, (const float4*)afrag, efrag, cand);
    rescore_kernel<<<N_VEC / 256, 256, 0, stream>>>(z_e, cb, esq, cand, zq, idxo, sse, counts);
    finalize_kernel<<<1, 256, 0, stream>>>(counts, sse, loss, perp);
}

// Round 13
// 102.652 us; speedup vs baseline: 1.3884x; 1.3884x over previous
//
#include <hip/hip_runtime.h>

#define N_VEC   131072
#define D       64
#define KCODES  1024
#define NT      64            // code tiles of 16
#define BLK     256
#define VPB     128           // vectors per block (32 per wave: 2 b-tiles)
#define CH      4             // code tiles staged per LDS chunk
#define NCH     (NT / CH)     // 16 chunks

typedef __attribute__((ext_vector_type(8))) short bf16x8;
typedef __attribute__((ext_vector_type(4))) float f32x4;

// direct global->LDS 16B DMA (no VGPR round trip; LDS dest linear in lane id)
#define GLD16(dst, src) __builtin_amdgcn_global_load_lds(                      \
    (const __attribute__((address_space(1))) void*)(src),                      \
    (__attribute__((address_space(3))) void*)(dst), 16, 0, 0)

// ws layout:
// [0,4096)          int counts[1024]
// [4096,4100)       float sse
// [5120,9216)       float esq[1024]
// [16384,81920)     float4 efrag[64*64]      (einit = -esq/2 in C-row fragment order)
// [81920,344064)    bf16x8 afrag[64*4*64]    (codebook hi/lo MFMA A-fragments)

__device__ __forceinline__ float4 f4fma(float4 a, float4 b, float4 c) {
    return make_float4(fmaf(a.x, b.x, c.x), fmaf(a.y, b.y, c.y),
                       fmaf(a.z, b.z, c.z), fmaf(a.w, b.w, c.w));
}
__device__ __forceinline__ float f4rsum(float4 a) {
    return (a.x + a.y) + (a.z + a.w);
}
__device__ __forceinline__ unsigned short f2bf(float f) {
    union { float f; unsigned u; } x; x.f = f;
    unsigned r = x.u + 0x7FFFu + ((x.u >> 16) & 1u);
    return (unsigned short)(r >> 16);
}
__device__ __forceinline__ float bf2f(unsigned short h) {
    union { unsigned u; float f; } x; x.u = ((unsigned)h) << 16;
    return x.f;
}
__device__ __forceinline__ int   f_as_i(float f) { union { float f; int i; } x; x.f = f; return x.i; }
__device__ __forceinline__ float i_as_f(int i)   { union { int i; float f; } x; x.i = i; return x.f; }

// esq + codebook MFMA A-fragments (hi/lo bf16 planes) + einit fragment table.
__global__ void prep_kernel(const float* __restrict__ cb, float* __restrict__ esq,
                            bf16x8* __restrict__ afrag, float4* __restrict__ efrag) {
    __shared__ float sesq[64];
    const int tid = threadIdx.x;
    const int c0  = blockIdx.x * 64;
    if (tid < 64) {
        const float4* c4 = reinterpret_cast<const float4*>(cb + (size_t)(c0 + tid) * D);
        float4 p = make_float4(0.f, 0.f, 0.f, 0.f);
        #pragma unroll
        for (int i = 0; i < 16; ++i) { float4 v = c4[i]; p = f4fma(v, v, p); }
        float e = f4rsum(p);
        esq[c0 + tid] = e;
        sesq[tid] = e;
    }
    __syncthreads();
    const int tt = tid >> 6;             // local tile 0..3
    const int L  = tid & 63;
    const int t  = blockIdx.x * 4 + tt;  // global tile
    const int g  = L >> 4;
    const int r  = t * 16 + (L & 15);
    #pragma unroll
    for (int ks = 0; ks < 2; ++ks) {
        const float* src = cb + (size_t)r * D + ks * 32 + g * 8;
        bf16x8 h, l;
        #pragma unroll
        for (int e = 0; e < 8; ++e) {
            float f = src[e];
            unsigned short hb = f2bf(f);
            float lo = f - bf2f(hb);
            h[e] = (short)hb;
            l[e] = (short)f2bf(lo);
        }
        afrag[(t * 4 + ks * 2 + 0) * 64 + L] = h;
        afrag[(t * 4 + ks * 2 + 1) * 64 + L] = l;
    }
    // einit = -esq/2 in C/D fragment layout (lane reg j <-> code row g*4+j)
    float4 ef;
    ef.x = -0.5f * sesq[tt * 16 + g * 4 + 0];
    ef.y = -0.5f * sesq[tt * 16 + g * 4 + 1];
    ef.z = -0.5f * sesq[tt * 16 + g * 4 + 2];
    ef.w = -0.5f * sesq[tt * 16 + g * 4 + 3];
    efrag[t * 64 + L] = ef;
}

// descending (value, idx) lexicographic insert into sorted-3 list
__device__ __forceinline__ void insd(float ov, int og,
                                     float& v0, float& v1, float& v2,
                                     int& g0, int& g1, int& g2) {
    bool b1 = (ov > v0) || (ov == v0 && og < g0);
    bool b2 = (ov > v1) || (ov == v1 && og < g1);
    bool b3 = (ov > v2) || (ov == v2 && og < g2);
    float nv2 = b2 ? v1 : (b3 ? ov : v2);
    int   ng2 = b2 ? g1 : (b3 ? og : g2);
    float nv1 = b1 ? v0 : (b2 ? ov : v1);
    int   ng1 = b1 ? g0 : (b2 ? og : g1);
    v0 = b1 ? ov : v0;
    g0 = b1 ? og : g0;
    v1 = nv1; g1 = ng1; v2 = nv2; g2 = ng2;
}

__launch_bounds__(BLK)
__global__ void vq_fused(const float* __restrict__ z_e, const float* __restrict__ cb,
                         const float* __restrict__ esq,
                         const float4* __restrict__ afrag4, const float4* __restrict__ efrag,
                         float* __restrict__ zq_out, float* __restrict__ idx_out,
                         float* __restrict__ sse, int* __restrict__ counts) {
    __shared__ float4 scb[2][CH * 4 * 64];   // 2 x 16 KB (double-buffered A-frags)
    __shared__ float4 sef[2][CH * 64];       // 2 x 4 KB  (einit frags)
    // epilogue overlays on scb[0] (dead after main loop + barrier); disjoint ranges:
    // scand [0,1536) | sZsq [2048,2560) | sS1 [2560,3072) | sS2 [3072,3584)
    // sC2  [3584,4096) | sred [4096,4112)
    char* ovl = (char*)&scb[0][0];
    int  (*scand)[3] = reinterpret_cast<int(*)[3]>(ovl);
    float* sZsq = reinterpret_cast<float*>(ovl + 2048);
    float* sS1  = reinterpret_cast<float*>(ovl + 2560);
    float* sS2  = reinterpret_cast<float*>(ovl + 3072);
    float* sC2  = reinterpret_cast<float*>(ovl + 3584);
    float* sred = reinterpret_cast<float*>(ovl + 4096);

    const int tid  = threadIdx.x;
    const int wave = tid >> 6;
    const int L    = tid & 63;
    const int lrow = L & 15;
    const int g    = L >> 4;
    const size_t vbase = (size_t)blockIdx.x * VPB + wave * 32;

    // ---- B-fragments: 2 vector-tiles of 16, hi/lo bf16 split, k = g*8+e ----
    bf16x8 zhi[2][2], zlo[2][2];
    #pragma unroll
    for (int b = 0; b < 2; ++b) {
        #pragma unroll
        for (int ks = 0; ks < 2; ++ks) {
            const float* zp = z_e + (vbase + b * 16 + lrow) * D + ks * 32 + g * 8;
            float4 u0 = *reinterpret_cast<const float4*>(zp);
            float4 u1 = *reinterpret_cast<const float4*>(zp + 4);
            float fv[8] = {u0.x, u0.y, u0.z, u0.w, u1.x, u1.y, u1.z, u1.w};
            bf16x8 h, l;
            #pragma unroll
            for (int e = 0; e < 8; ++e) {
                unsigned short hb = f2bf(fv[e]);
                float lo = fv[e] - bf2f(hb);
                h[e] = (short)hb;
                l[e] = (short)f2bf(lo);
            }
            zhi[b][ks] = h; zlo[b][ks] = l;
        }
    }

    // packed top-3 stream state (r-domain: larger = nearer code)
    float m1[2], m2[2], m3[2];
    #pragma unroll
    for (int b = 0; b < 2; ++b) { m1[b] = m2[b] = m3[b] = -INFINITY; }

    // prologue: stage chunk 0 into buffer 0
    #pragma unroll
    for (int i = 0; i < 4; ++i) GLD16(&scb[0][i * BLK + tid], afrag4 + i * BLK + tid);
    GLD16(&sef[0][tid], efrag + tid);

    int cur = 0;
    for (int c = 0; c < NCH; ++c) {
        __syncthreads();   // drains vmcnt -> buf[cur] ready; prev compute done
        if (c + 1 < NCH) {
            const float4* gA = afrag4 + (size_t)(c + 1) * (CH * 4 * 64);
            const float4* gE = efrag + (size_t)(c + 1) * (CH * 64);
            #pragma unroll
            for (int i = 0; i < 4; ++i) GLD16(&scb[cur ^ 1][i * BLK + tid], gA + i * BLK + tid);
            GLD16(&sef[cur ^ 1][tid], gE + tid);
        }

        #pragma unroll
        for (int tt = 0; tt < CH; ++tt) {
            const int t = c * CH + tt;
            const bf16x8* fr = reinterpret_cast<const bf16x8*>(&scb[cur][tt * 256]);
            bf16x8 Ah0 = fr[0 * 64 + L];
            bf16x8 Al0 = fr[1 * 64 + L];
            bf16x8 Ah1 = fr[2 * 64 + L];
            bf16x8 Al1 = fr[3 * 64 + L];
            f32x4 einit;
            {
                float4 ef = sef[cur][tt * 64 + L];   // -esq/2
                einit[0] = ef.x; einit[1] = ef.y; einit[2] = ef.z; einit[3] = ef.w;
            }

            #pragma unroll
            for (int b = 0; b < 2; ++b) {
                // single 6-deep chain; C-init = -esq/2 -> acc = dot - esq/2
                f32x4 acc;
                acc = __builtin_amdgcn_mfma_f32_16x16x32_bf16(Ah0, zhi[b][0], einit, 0, 0, 0);
                acc = __builtin_amdgcn_mfma_f32_16x16x32_bf16(Ah0, zlo[b][0], acc, 0, 0, 0);
                acc = __builtin_amdgcn_mfma_f32_16x16x32_bf16(Al0, zhi[b][0], acc, 0, 0, 0);
                acc = __builtin_amdgcn_mfma_f32_16x16x32_bf16(Ah1, zhi[b][1], acc, 0, 0, 0);
                acc = __builtin_amdgcn_mfma_f32_16x16x32_bf16(Ah1, zlo[b][1], acc, 0, 0, 0);
                acc = __builtin_amdgcn_mfma_f32_16x16x32_bf16(Al1, zhi[b][1], acc, 0, 0, 0);

                #pragma unroll
                for (int j = 0; j < 4; ++j) {
                    // pack 8-bit local id (complement: fmax prefers lower code)
                    int komp = 255 - ((t << 2) | j);   // wave-uniform SGPR
                    float pd = i_as_f((f_as_i(acc[j]) & 0xFFFFFF00) | komp);  // v_and_or
                    // 4-op top-3 insert (min + med3 + 2 max)
                    float mn = fminf(m2[b], pd);
                    float md = __builtin_amdgcn_fmed3f(m1[b], pd, m2[b]);
                    m1[b] = fmaxf(m1[b], pd);
                    m2[b] = md;
                    m3[b] = fmaxf(m3[b], mn);
                }
            }
        }
        cur ^= 1;
    }

    __syncthreads();   // all waves done with scb -> overlays safe

    // ---- decode + cross-lane (4 g-groups) merge with global-idx tie-break ----
    #pragma unroll
    for (int b = 0; b < 2; ++b) {
        float v0, v1, v2; int g0, g1, g2;
        {
            int p0 = f_as_i(m1[b]), p1 = f_as_i(m2[b]), p2 = f_as_i(m3[b]);
            int c0 = 255 - (p0 & 255), c1 = 255 - (p1 & 255), c2 = 255 - (p2 & 255);
            v0 = i_as_f(p0 & ~255); g0 = (c0 >> 2) * 16 + g * 4 + (c0 & 3);
            v1 = i_as_f(p1 & ~255); g1 = (c1 >> 2) * 16 + g * 4 + (c1 & 3);
            v2 = i_as_f(p2 & ~255); g2 = (c2 >> 2) * 16 + g * 4 + (c2 & 3);
        }
        #pragma unroll
        for (int m = 16; m <= 32; m <<= 1) {
            float ov0 = __shfl_xor(v0, m), ov1 = __shfl_xor(v1, m), ov2 = __shfl_xor(v2, m);
            int   og0 = __shfl_xor(g0, m), og1 = __shfl_xor(g1, m), og2 = __shfl_xor(g2, m);
            insd(ov0, og0, v0, v1, v2, g0, g1, g2);
            insd(ov1, og1, v0, v1, v2, g0, g1, g2);
            insd(ov2, og2, v0, v1, v2, g0, g1, g2);
        }
        if (g == 0) {
            int lv = wave * 32 + b * 16 + lrow;
            scand[lv][0] = g0; scand[lv][1] = g1; scand[lv][2] = g2;
        }
    }
    __syncthreads();

    // ---- fused exact rescore (bit-replicates reference), 2 threads/vector ----
    const int vid = tid & (VPB - 1);
    const int sub = tid >> 7;
    const size_t n = (size_t)blockIdx.x * VPB + vid;
    {
        const float4* z4 = reinterpret_cast<const float4*>(z_e + n * D);
        if (sub == 0) {
            // zsq + dot(cand0)
            int ci0 = scand[vid][0];
            const float4* cp0 = reinterpret_cast<const float4*>(cb + (size_t)ci0 * D);
            float4 pq = make_float4(0.f, 0.f, 0.f, 0.f);
            float4 s0 = pq;
            #pragma unroll
            for (int i = 0; i < 16; ++i) {
                float4 zz = z4[i];
                pq = f4fma(zz, zz, pq);
                s0 = f4fma(zz, cp0[i], s0);
            }
            sZsq[vid] = f4rsum(pq);
            sS1[vid]  = f4rsum(s0);   // cand0 dot
        } else {
            // dot(cand1), dot(cand2)
            int ci1 = scand[vid][1];
            int ci2 = scand[vid][2];
            const float4* cp1 = reinterpret_cast<const float4*>(cb + (size_t)ci1 * D);
            const float4* cp2 = reinterpret_cast<const float4*>(cb + (size_t)ci2 * D);
            float4 s1 = make_float4(0.f, 0.f, 0.f, 0.f);
            float4 s2 = s1;
            #pragma unroll
            for (int i = 0; i < 16; ++i) {
                float4 zz = z4[i];
                s1 = f4fma(zz, cp1[i], s1);
                s2 = f4fma(zz, cp2[i], s2);
            }
            sS2[vid] = f4rsum(s1);    // cand1 dot
            sC2[vid] = f4rsum(s2);    // cand2 dot
        }
    }
    __syncthreads();

    float v = 0.f;
    if (sub == 0) {
        int ci0 = scand[vid][0], ci1 = scand[vid][1], ci2 = scand[vid][2];
        float zsq = sZsq[vid];
        float d0 = fmaf(-2.0f, sS1[vid], zsq + esq[ci0]);
        float d1 = fmaf(-2.0f, sS2[vid], zsq + esq[ci1]);
        float d2 = fmaf(-2.0f, sC2[vid], zsq + esq[ci2]);
        float bd = d0; int bi = ci0;
        if (d1 < bd || (d1 == bd && ci1 < bi)) { bd = d1; bi = ci1; }
        if (d2 < bd || (d2 == bd && ci2 < bi)) { bd = d2; bi = ci2; }
        idx_out[n] = (float)bi;
        atomicAdd(&counts[bi], 1);
        scand[vid][0] = bi;            // winner (scand slot reused)
        v = bd;
    }
    #pragma unroll
    for (int off = 32; off > 0; off >>= 1) v += __shfl_down(v, off);
    if ((tid & 63) == 0) sred[tid >> 6] = v;
    __syncthreads();   // winners + sred ready
    if (tid == 0) atomicAdd(sse, (sred[0] + sred[1]) + (sred[2] + sred[3]));

    // ---- coalesced z_q write: 128 vectors * 16 float4 ----
    const float4* cb4 = reinterpret_cast<const float4*>(cb);
    float4* zq4 = reinterpret_cast<float4*>(zq_out) + (size_t)blockIdx.x * (VPB * 16);
    #pragma unroll
    for (int i = 0; i < 8; ++i) {
        int mi  = i * BLK + tid;      // 0..2047
        int vec = mi >> 4;
        int e   = mi & 15;
        zq4[mi] = cb4[(size_t)scand[vec][0] * 16 + e];
    }
}

__global__ void finalize_kernel(const int* __restrict__ counts, const float* __restrict__ sse,
                                float* __restrict__ out_loss, float* __restrict__ out_perp) {
    __shared__ float red[256];
    int tid = threadIdx.x;
    float hsum = 0.f;
    for (int k = tid; k < KCODES; k += 256) {
        float p = (float)counts[k] / (float)N_VEC;
        hsum += p * logf(p + 1e-12f);
    }
    red[tid] = hsum;
    __syncthreads();
    for (int s = 128; s > 0; s >>= 1) {
        if (tid < s) red[tid] += red[tid + s];
        __syncthreads();
    }
    if (tid == 0) {
        out_loss[0] = 1.25f * sse[0] / 8388608.0f;   // (1+BETA) * mean
        out_perp[0] = expf(-red[0]);
    }
}

extern "C" void kernel_launch(void* const* d_in, const int* in_sizes, int n_in,
                              void* d_out, int out_size, void* d_ws, size_t ws_size,
                              hipStream_t stream) {
    const float* z_e = (const float*)d_in[0];
    const float* cb  = (const float*)d_in[1];

    float* out  = (float*)d_out;
    float* zq   = out;
    float* idxo = out + (size_t)N_VEC * D;          // 8388608
    float* loss = idxo + N_VEC;                     // +131072
    float* perp = loss + 1;

    char* ws = (char*)d_ws;
    int*    counts = (int*)ws;
    float*  sse    = (float*)(ws + 4096);
    float*  esq    = (float*)(ws + 5120);
    float4* efrag  = (float4*)(ws + 16384);
    bf16x8* afrag  = (bf16x8*)(ws + 81920);

    hipMemsetAsync(d_ws, 0, 5120, stream);          // zero counts + sse each call
    prep_kernel<<<16, 256, 0, stream>>>(cb, esq, afrag, efrag);
    vq_fused<<<N_VEC / VPB, BLK, 0, stream>>>(z_e, cb, esq, (const float4*)afrag, efrag,
                                              zq, idxo, sse, counts);
    finalize_kernel<<<1, 256, 0, stream>>>(counts, sse, loss, perp);
}